// Round 2
// baseline (7276.009 us; speedup 1.0000x reference)
//
#include <hip/hip_runtime.h>
#include <hip/hip_bf16.h>

// L=512, B=64, D=H=512, 3H=1536.
// Pipeline:
//  gemm_k<SPLIT,TANH>: Pt = tanh(v@Wp^T), Qt = tanh(v@Wp_^T)  (split-bf16 3-pass MFMA, f32 out)
//  att_k: s[t][l] = sum_h Vb*(A+B)/(1+A*B) (tanh addition formula), softmax over l,
//         c[t][b][:] = sum_l a*v[l][b][:]   (fused; c stored bf16)
//  gemm_k<AIN_BF16,BIAS,OUTBF16>: Gi = c@W_ih^T + b_ih  (bf16 out)
//  rec_k: grouped persistent GRU recurrence (8 groups x 32 one-wave blocks),
//         W_hh slice register-resident as MFMA A-frags, per-step spin barrier.

typedef float f32x4 __attribute__((ext_vector_type(4)));
typedef short s16x8 __attribute__((ext_vector_type(8)));
typedef short s16x4 __attribute__((ext_vector_type(4)));

static __device__ __forceinline__ float rcp_fast(float x) { return __builtin_amdgcn_rcpf(x); }
static __device__ __forceinline__ float tanh_fast(float x) {
    float e = __expf(2.0f * x);
    return 1.0f - 2.0f * rcp_fast(e + 1.0f);
}
static __device__ __forceinline__ float sigmoid_fast(float x) {
    return rcp_fast(1.0f + __expf(-x));
}
static __device__ __forceinline__ unsigned short f2bf(float x) {
    union { float f; unsigned u; } v; v.f = x;
    unsigned r = v.u + 0x7FFFu + ((v.u >> 16) & 1u);
    return (unsigned short)(r >> 16);
}
static __device__ __forceinline__ float bf2f(unsigned short b) {
    union { unsigned u; float f; } v; v.u = ((unsigned)b) << 16;
    return v.f;
}
static __device__ __forceinline__ s16x8 pack8(f32x4 a, f32x4 b) {
    s16x8 r;
    r[0] = (short)f2bf(a[0]); r[1] = (short)f2bf(a[1]);
    r[2] = (short)f2bf(a[2]); r[3] = (short)f2bf(a[3]);
    r[4] = (short)f2bf(b[0]); r[5] = (short)f2bf(b[1]);
    r[6] = (short)f2bf(b[2]); r[7] = (short)f2bf(b[3]);
    return r;
}
// split x into hi (bf16) and lo (bf16 of residual)
static __device__ __forceinline__ void split8(f32x4 a, f32x4 b, s16x8* hi, s16x8* lo) {
    s16x8 h, l;
#pragma unroll
    for (int e = 0; e < 4; e++) {
        unsigned short hh = f2bf(a[e]); h[e] = (short)hh;
        l[e] = (short)f2bf(a[e] - bf2f(hh));
    }
#pragma unroll
    for (int e = 0; e < 4; e++) {
        unsigned short hh = f2bf(b[e]); h[4 + e] = (short)hh;
        l[4 + e] = (short)f2bf(b[e] - bf2f(hh));
    }
    *hi = h; *lo = l;
}
static __device__ __forceinline__ f32x4 mfma16(s16x8 a, s16x8 b, f32x4 c) {
    return __builtin_amdgcn_mfma_f32_16x16x32_bf16(a, b, c, 0, 0, 0);
}

// ---------------------------------------------------------------------------
// C[m][n] = A[m][:]·W[n][:] (+bias) (tanh?) ; K = 512 fixed.
// 128x128 tile, BK=64, 4 waves, each wave 64x64 (4x4 16x16x32 MFMA frags).
// SPLIT=1: A,W staged as hi+lo bf16, 3 MFMA passes (f32-grade product).
// AIN=1: A is already bf16 (row stride 512).
// ---------------------------------------------------------------------------
template<int SPLIT, int TANH, int BIAS, int AIN, int OUTBF16>
__global__ __launch_bounds__(256, 2)
void gemm_k(const void* __restrict__ Ap, const float* __restrict__ Wp,
            const float* __restrict__ bias, void* __restrict__ outp,
            int M, int N)
{
    const int bm = blockIdx.x, bn = blockIdx.y;
    const int tid = threadIdx.x;
    const int w = tid >> 6, lane = tid & 63;
    const int l15 = lane & 15, l4 = lane >> 4;

    __shared__ unsigned short Al[128 * 72 * (SPLIT ? 2 : 1)];
    __shared__ unsigned short Wl[128 * 72 * (SPLIT ? 2 : 1)];
    const int LOFS = 128 * 72;   // lo-plane offset (elems)

    f32x4 acc[4][4];
#pragma unroll
    for (int i = 0; i < 4; i++)
#pragma unroll
        for (int j = 0; j < 4; j++) acc[i][j] = (f32x4){0.f, 0.f, 0.f, 0.f};

    const int srow = tid >> 1, shalf = tid & 1;
    const float* Asrc = (const float*)Ap + (size_t)(bm * 128 + srow) * 512 + shalf * 32;
    const unsigned short* Asrcb = (const unsigned short*)Ap + (size_t)(bm * 128 + srow) * 512 + shalf * 32;
    const float* Wsrc = Wp + (size_t)(bn * 128 + srow) * 512 + shalf * 32;
    unsigned short* Adst = Al + srow * 72 + shalf * 32;
    unsigned short* Wdst = Wl + srow * 72 + shalf * 32;

    for (int k0 = 0; k0 < 512; k0 += 64) {
        __syncthreads();
        if (AIN) {
#pragma unroll
            for (int j = 0; j < 4; j++)
                *(s16x8*)(Adst + j * 8) = *(const s16x8*)(Asrcb + k0 + j * 8);
        } else if (SPLIT) {
#pragma unroll
            for (int j = 0; j < 4; j++) {
                f32x4 x = *(const f32x4*)(Asrc + k0 + j * 8);
                f32x4 y = *(const f32x4*)(Asrc + k0 + j * 8 + 4);
                s16x8 hi, lo; split8(x, y, &hi, &lo);
                *(s16x8*)(Adst + j * 8) = hi;
                *(s16x8*)(Adst + LOFS + j * 8) = lo;
            }
        } else {
#pragma unroll
            for (int j = 0; j < 4; j++) {
                f32x4 x = *(const f32x4*)(Asrc + k0 + j * 8);
                f32x4 y = *(const f32x4*)(Asrc + k0 + j * 8 + 4);
                *(s16x8*)(Adst + j * 8) = pack8(x, y);
            }
        }
        if (SPLIT) {
#pragma unroll
            for (int j = 0; j < 4; j++) {
                f32x4 x = *(const f32x4*)(Wsrc + k0 + j * 8);
                f32x4 y = *(const f32x4*)(Wsrc + k0 + j * 8 + 4);
                s16x8 hi, lo; split8(x, y, &hi, &lo);
                *(s16x8*)(Wdst + j * 8) = hi;
                *(s16x8*)(Wdst + LOFS + j * 8) = lo;
            }
        } else {
#pragma unroll
            for (int j = 0; j < 4; j++) {
                f32x4 x = *(const f32x4*)(Wsrc + k0 + j * 8);
                f32x4 y = *(const f32x4*)(Wsrc + k0 + j * 8 + 4);
                *(s16x8*)(Wdst + j * 8) = pack8(x, y);
            }
        }
        __syncthreads();

#pragma unroll
        for (int kt = 0; kt < 2; kt++) {
            s16x8 afh[4], bfh[4];
#pragma unroll
            for (int mb = 0; mb < 4; mb++)
                afh[mb] = *(const s16x8*)(Al + ((w & 1) * 64 + mb * 16 + l15) * 72 + kt * 32 + l4 * 8);
#pragma unroll
            for (int nb = 0; nb < 4; nb++)
                bfh[nb] = *(const s16x8*)(Wl + ((w >> 1) * 64 + nb * 16 + l15) * 72 + kt * 32 + l4 * 8);
            if (SPLIT) {
                s16x8 afl[4], bfl[4];
#pragma unroll
                for (int mb = 0; mb < 4; mb++)
                    afl[mb] = *(const s16x8*)(Al + LOFS + ((w & 1) * 64 + mb * 16 + l15) * 72 + kt * 32 + l4 * 8);
#pragma unroll
                for (int nb = 0; nb < 4; nb++)
                    bfl[nb] = *(const s16x8*)(Wl + LOFS + ((w >> 1) * 64 + nb * 16 + l15) * 72 + kt * 32 + l4 * 8);
#pragma unroll
                for (int mb = 0; mb < 4; mb++)
#pragma unroll
                    for (int nb = 0; nb < 4; nb++) {
                        acc[mb][nb] = mfma16(afh[mb], bfh[nb], acc[mb][nb]);
                        acc[mb][nb] = mfma16(afh[mb], bfl[nb], acc[mb][nb]);
                        acc[mb][nb] = mfma16(afl[mb], bfh[nb], acc[mb][nb]);
                    }
            } else {
#pragma unroll
                for (int mb = 0; mb < 4; mb++)
#pragma unroll
                    for (int nb = 0; nb < 4; nb++)
                        acc[mb][nb] = mfma16(afh[mb], bfh[nb], acc[mb][nb]);
            }
        }
    }

    const int m0 = bm * 128 + (w & 1) * 64;
    const int n0 = bn * 128 + (w >> 1) * 64;
#pragma unroll
    for (int nb = 0; nb < 4; nb++) {
        float bv = 0.0f;
        const int n = n0 + nb * 16 + l15;
        if (BIAS) bv = bias[n];
#pragma unroll
        for (int mb = 0; mb < 4; mb++) {
#pragma unroll
            for (int i = 0; i < 4; i++) {
                const int m = m0 + mb * 16 + l4 * 4 + i;
                float vv = acc[mb][nb][i];
                if (BIAS) vv += bv;
                if (TANH) vv = tanh_fast(vv);
                if (OUTBF16) ((unsigned short*)outp)[(size_t)m * N + n] = f2bf(vv);
                else        ((float*)outp)[(size_t)m * N + n] = vv;
            }
        }
    }
}

// ---------------------------------------------------------------------------
// Fused attention: block = (t-tile of 16, b). 512 threads.
// lane: t_in = lane>>5 (2 t's per wave), sl = lane&31 (32 h/d-slices of 16).
// Phase A: s[t][l] via tanh addition formula; Phase B: softmax; Phase C: c (bf16 out).
// LDS gap mapping f' = f + 4*(f>>4) keeps b128 reads conflict-clean.
// ---------------------------------------------------------------------------
__global__ __launch_bounds__(512, 4)
void att_k(const float* __restrict__ Pt, const float* __restrict__ Qt,
           const float* __restrict__ Vv, const float* __restrict__ vin,
           unsigned short* __restrict__ cbuf)
{
    const int tblk = blockIdx.x, b = blockIdx.y;
    const int tid = threadIdx.x;
    const int w = tid >> 6, lane = tid & 63;
    const int t_in = lane >> 5, sl = lane & 31;
    const int t_loc = w * 2 + t_in;          // 0..15
    const int tg = tblk * 16 + t_loc;        // global t

    __shared__ float sbuf[16][513];
    __shared__ float qst[8][640];
    __shared__ float zinv[16];

    float Pa[16], Vb[16], VbA[16];
    {
        const float* pp = Pt + ((size_t)tg * 64 + b) * 512 + sl * 16;
        const float* vb = Vv + (size_t)b * 512 + sl * 16;
#pragma unroll
        for (int j = 0; j < 4; j++) {
            f32x4 x = *(const f32x4*)(pp + j * 4);
            f32x4 y = *(const f32x4*)(vb + j * 4);
#pragma unroll
            for (int e = 0; e < 4; e++) { Pa[j * 4 + e] = x[e]; Vb[j * 4 + e] = y[e]; }
        }
#pragma unroll
        for (int e = 0; e < 16; e++) VbA[e] = Vb[e] * Pa[e];
    }

    // ---- Phase A: logits ----
    for (int l0 = 0; l0 < 512; l0 += 8) {
        __syncthreads();
        {
            const int row = tid >> 6;
            const int cb = (tid & 63) * 8;
            const float* src = Qt + ((size_t)(l0 + row) * 64 + b) * 512 + cb;
            const int f0 = cb + 4 * (cb >> 4);
            *(f32x4*)(&qst[row][f0])     = *(const f32x4*)(src);
            *(f32x4*)(&qst[row][f0 + 4]) = *(const f32x4*)(src + 4);
        }
        __syncthreads();
        for (int l = 0; l < 8; l++) {
            const float* qrow = &qst[l][sl * 20];
            float a0 = 0.f, a1 = 0.f, a2 = 0.f, a3 = 0.f;
#pragma unroll
            for (int j = 0; j < 4; j++) {
                f32x4 q = *(const f32x4*)(qrow + j * 4);
                {
                    float d = fmaxf(fmaf(Pa[4 * j + 0], q[0], 1.0f), 1e-20f);
                    a0 = fmaf(fmaf(Vb[4 * j + 0], q[0], VbA[4 * j + 0]), rcp_fast(d), a0);
                }
                {
                    float d = fmaxf(fmaf(Pa[4 * j + 1], q[1], 1.0f), 1e-20f);
                    a1 = fmaf(fmaf(Vb[4 * j + 1], q[1], VbA[4 * j + 1]), rcp_fast(d), a1);
                }
                {
                    float d = fmaxf(fmaf(Pa[4 * j + 2], q[2], 1.0f), 1e-20f);
                    a2 = fmaf(fmaf(Vb[4 * j + 2], q[2], VbA[4 * j + 2]), rcp_fast(d), a2);
                }
                {
                    float d = fmaxf(fmaf(Pa[4 * j + 3], q[3], 1.0f), 1e-20f);
                    a3 = fmaf(fmaf(Vb[4 * j + 3], q[3], VbA[4 * j + 3]), rcp_fast(d), a3);
                }
            }
            float accp = (a0 + a1) + (a2 + a3);
#pragma unroll
            for (int m = 1; m < 32; m <<= 1) accp += __shfl_xor(accp, m, 64);
            if (sl == 0) sbuf[t_loc][l0 + l] = accp;
        }
    }
    __syncthreads();

    // ---- Phase B: softmax over l ----
    {
        const int tr = tid >> 5;
        const int i = tid & 31;
        float m = -1e30f;
        for (int l = i; l < 512; l += 32) m = fmaxf(m, sbuf[tr][l]);
#pragma unroll
        for (int mm = 1; mm < 32; mm <<= 1) m = fmaxf(m, __shfl_xor(m, mm, 64));
        float z = 0.0f;
        for (int l = i; l < 512; l += 32) {
            float e = __expf(sbuf[tr][l] - m);
            sbuf[tr][l] = e;
            z += e;
        }
#pragma unroll
        for (int mm = 1; mm < 32; mm <<= 1) z += __shfl_xor(z, mm, 64);
        if (i == 0) zinv[tr] = rcp_fast(z);
    }
    __syncthreads();

    // ---- Phase C: c[t][b][:] ----
    float ca[16];
#pragma unroll
    for (int j = 0; j < 16; j++) ca[j] = 0.0f;

    for (int l0 = 0; l0 < 512; l0 += 8) {
        __syncthreads();
        {
            const int row = tid >> 6;
            const int cb = (tid & 63) * 8;
            const float* src = vin + ((size_t)(l0 + row) * 64 + b) * 512 + cb;
            const int f0 = cb + 4 * (cb >> 4);
            *(f32x4*)(&qst[row][f0])     = *(const f32x4*)(src);
            *(f32x4*)(&qst[row][f0 + 4]) = *(const f32x4*)(src + 4);
        }
        __syncthreads();
        for (int l = 0; l < 8; l++) {
            const float a = sbuf[t_loc][l0 + l];
            const float* vrow = &qst[l][sl * 20];
#pragma unroll
            for (int j = 0; j < 4; j++) {
                f32x4 x = *(const f32x4*)(vrow + j * 4);
                ca[4 * j + 0] = fmaf(a, x[0], ca[4 * j + 0]);
                ca[4 * j + 1] = fmaf(a, x[1], ca[4 * j + 1]);
                ca[4 * j + 2] = fmaf(a, x[2], ca[4 * j + 2]);
                ca[4 * j + 3] = fmaf(a, x[3], ca[4 * j + 3]);
            }
        }
    }
    const float zi = zinv[t_loc];
    unsigned short* co = cbuf + ((size_t)tg * 64 + b) * 512 + sl * 16;
#pragma unroll
    for (int j = 0; j < 4; j++) {
        s16x4 o;
        o[0] = (short)f2bf(ca[4 * j + 0] * zi);
        o[1] = (short)f2bf(ca[4 * j + 1] * zi);
        o[2] = (short)f2bf(ca[4 * j + 2] * zi);
        o[3] = (short)f2bf(ca[4 * j + 3] * zi);
        *(s16x4*)(co + j * 4) = o;
    }
}

// ---------------------------------------------------------------------------
// GRU recurrence. 256 one-wave blocks: group grp = bid&7 (8 b's), sub sb = bid>>3
// owns output slice jj = sb*16. W_hh slice register-resident as MFMA A-frags.
// ---------------------------------------------------------------------------
__global__ __launch_bounds__(64, 1)
void rec_k(const unsigned short* __restrict__ Gi,
           const float* __restrict__ Whh, const float* __restrict__ bhh,
           const float* __restrict__ h0,
           unsigned short* __restrict__ hbf,
           unsigned int* __restrict__ bar,
           float* __restrict__ hs)
{
    const int grp = blockIdx.x & 7;
    const int sb = blockIdx.x >> 3;      // 0..31
    const int lane = threadIdx.x;
    const int l15 = lane & 15, l4 = lane >> 4;
    const int jj = sb * 16;
    const int bcol = l15 & 7;
    const int b = grp * 8 + bcol;
    const int jrow = l4 * 4;

    s16x8 wf[3][16];
#pragma unroll
    for (int g = 0; g < 3; g++) {
        const float* wr = Whh + (size_t)(g * 512 + jj + l15) * 512 + l4 * 8;
#pragma unroll
        for (int kt = 0; kt < 16; kt++) {
            f32x4 x = *(const f32x4*)(wr + kt * 32);
            f32x4 y = *(const f32x4*)(wr + kt * 32 + 4);
            wf[g][kt] = pack8(x, y);
        }
    }

    float bh_r[4], bh_z[4], bh_n[4];
#pragma unroll
    for (int i = 0; i < 4; i++) {
        bh_r[i] = bhh[jj + jrow + i];
        bh_z[i] = bhh[512 + jj + jrow + i];
        bh_n[i] = bhh[1024 + jj + jrow + i];
    }
    float hp[4];
    {
        f32x4 x = *(const f32x4*)(h0 + (size_t)b * 512 + jj + jrow);
        hp[0] = x[0]; hp[1] = x[1]; hp[2] = x[2]; hp[3] = x[3];
    }
    unsigned int* mybar = bar + grp * 512;
    bool gaveup = false;

    for (int t = 0; t < 512; t++) {
        s16x8 hfrag[16];
        if (t == 0) {
            const float* hr = h0 + (size_t)b * 512 + l4 * 8;
#pragma unroll
            for (int kt = 0; kt < 16; kt++) {
                f32x4 x = *(const f32x4*)(hr + kt * 32);
                f32x4 y = *(const f32x4*)(hr + kt * 32 + 4);
                hfrag[kt] = pack8(x, y);
            }
        } else {
            const unsigned short* hr = hbf + ((size_t)((t & 1) * 64 + b)) * 512 + l4 * 8;
#pragma unroll
            for (int kt = 0; kt < 16; kt++)
                hfrag[kt] = *(const s16x8*)(hr + kt * 32);
        }

        const unsigned short* gp = Gi + ((size_t)t * 64 + b) * 1536 + jj + jrow;
        s16x4 g0 = *(const s16x4*)(gp);
        s16x4 g1 = *(const s16x4*)(gp + 512);
        s16x4 g2 = *(const s16x4*)(gp + 1024);

        f32x4 acc0 = {0.f, 0.f, 0.f, 0.f};
        f32x4 acc1 = {0.f, 0.f, 0.f, 0.f};
        f32x4 acc2 = {0.f, 0.f, 0.f, 0.f};
#pragma unroll
        for (int kt = 0; kt < 16; kt++) {
            acc0 = mfma16(wf[0][kt], hfrag[kt], acc0);
            acc1 = mfma16(wf[1][kt], hfrag[kt], acc1);
            acc2 = mfma16(wf[2][kt], hfrag[kt], acc2);
        }

        if (l15 < 8) {
            float* hso = hs + ((size_t)t * 64 + b) * 512 + jj + jrow;
            unsigned short* hbo = hbf + ((size_t)(((t + 1) & 1) * 64 + b)) * 512 + jj + jrow;
            f32x4 hv; s16x4 hb;
#pragma unroll
            for (int i = 0; i < 4; i++) {
                float rr = sigmoid_fast(bf2f((unsigned short)g0[i]) + acc0[i] + bh_r[i]);
                float zz = sigmoid_fast(bf2f((unsigned short)g1[i]) + acc1[i] + bh_z[i]);
                float nn = tanh_fast(bf2f((unsigned short)g2[i]) + rr * (acc2[i] + bh_n[i]));
                float hn = fmaf(zz, hp[i] - nn, nn);
                hp[i] = hn;
                hv[i] = hn;
                hb[i] = (short)f2bf(hn);
            }
            *(f32x4*)hso = hv;
            *(s16x4*)hbo = hb;
        }

        if (t < 511 && !gaveup) {
            if (lane == 0)
                __hip_atomic_fetch_add(mybar + t, 1u, __ATOMIC_RELEASE, __HIP_MEMORY_SCOPE_AGENT);
            unsigned spin = 0;
            while (__hip_atomic_load(mybar + t, __ATOMIC_ACQUIRE, __HIP_MEMORY_SCOPE_AGENT) < 32u) {
                __builtin_amdgcn_s_sleep(1);
                if (++spin > (1u << 22)) { gaveup = true; break; }  // hang safety
            }
        }
    }
}

// ---------------------------------------------------------------------------
// ws layout (bytes):
//   Pt : [0, 64Mi)            f32  L*B x 512
//   Qt : [64Mi, 128Mi)        f32
//   c  : [128Mi, 160Mi)       bf16 L*B x 512
//   Gi : [0, 96Mi)            bf16 L*B x 1536  (overlays Pt/Qt, dead by then)
//   hbf: [160Mi, +128Ki)      bf16 2 x 64 x 512
//   bar: [160Mi+128Ki, +16Ki) u32  8 x 512
// total ~160.2 MiB
// ---------------------------------------------------------------------------
extern "C" void kernel_launch(void* const* d_in, const int* in_sizes, int n_in,
                              void* d_out, int out_size, void* d_ws, size_t ws_size,
                              hipStream_t stream)
{
    (void)in_sizes; (void)n_in; (void)out_size; (void)ws_size;
    const float* v   = (const float*)d_in[0];
    const float* h0  = (const float*)d_in[1];
    const float* Vv  = (const float*)d_in[2];
    const float* Wp  = (const float*)d_in[3];
    const float* Wp_ = (const float*)d_in[4];
    const float* Wih = (const float*)d_in[5];
    const float* Whh = (const float*)d_in[6];
    const float* bih = (const float*)d_in[7];
    const float* bhh = (const float*)d_in[8];
    float* hs = (float*)d_out;

    char* ws = (char*)d_ws;
    float* Pt = (float*)(ws);
    float* Qt = (float*)(ws + 67108864ULL);
    unsigned short* cb  = (unsigned short*)(ws + 134217728ULL);
    unsigned short* Gi  = (unsigned short*)(ws);
    unsigned short* hbf = (unsigned short*)(ws + 167772160ULL);
    unsigned int*   bar = (unsigned int*)(ws + 167772160ULL + 131072ULL);

    hipMemsetAsync(bar, 0, 4096 * sizeof(unsigned int), stream);

    dim3 gpq(256, 4, 1);
    gemm_k<1, 1, 0, 0, 0><<<gpq, 256, 0, stream>>>(v, Wp, nullptr, Pt, 32768, 512);
    gemm_k<1, 1, 0, 0, 0><<<gpq, 256, 0, stream>>>(v, Wp_, nullptr, Qt, 32768, 512);

    att_k<<<dim3(32, 64), 512, 0, stream>>>(Pt, Qt, Vv, v, cb);

    gemm_k<0, 0, 1, 1, 1><<<dim3(256, 12), 256, 0, stream>>>(cb, Wih, bih, Gi, 32768, 1536);

    rec_k<<<dim3(256), 64, 0, stream>>>(Gi, Whh, bhh, h0, hbf, bar, hs);
}

// Round 3
// 6295.319 us; speedup vs baseline: 1.1558x; 1.1558x over previous
//
#include <hip/hip_runtime.h>
#include <hip/hip_bf16.h>

// L=512, B=64, D=H=512, 3H=1536.
// Pipeline:
//  gemm_k<SPLIT,TANH>: Pt = tanh(v@Wp^T), Qt = tanh(v@Wp_^T)  (split-bf16 3-pass MFMA, f32 out)
//  att_k: s[t][l] = sum_h Vb*(A+B)/(1+A*B) (tanh addition formula), softmax over l,
//         c[t][b][:] = sum_l a*v[l][b][:]   (fused; c stored bf16)
//  gemm_k<AIN_BF16,BIAS,OUTBF16>: Gi = c@W_ih^T + b_ih  (bf16 out)
//  rec_k: grouped persistent GRU recurrence (8 groups x 32 one-wave blocks),
//         W_hh slice register-resident as MFMA A-frags.
//         Sync: relaxed polls + one release/acquire fence pair per step
//         (r2's per-poll acquire caused 166 GB of coherence traffic).

typedef float f32x4 __attribute__((ext_vector_type(4)));
typedef short s16x8 __attribute__((ext_vector_type(8)));
typedef short s16x4 __attribute__((ext_vector_type(4)));

static __device__ __forceinline__ float rcp_fast(float x) { return __builtin_amdgcn_rcpf(x); }
static __device__ __forceinline__ float tanh_fast(float x) {
    float e = __expf(2.0f * x);
    return 1.0f - 2.0f * rcp_fast(e + 1.0f);
}
static __device__ __forceinline__ float sigmoid_fast(float x) {
    return rcp_fast(1.0f + __expf(-x));
}
static __device__ __forceinline__ unsigned short f2bf(float x) {
    union { float f; unsigned u; } v; v.f = x;
    unsigned r = v.u + 0x7FFFu + ((v.u >> 16) & 1u);
    return (unsigned short)(r >> 16);
}
static __device__ __forceinline__ float bf2f(unsigned short b) {
    union { unsigned u; float f; } v; v.u = ((unsigned)b) << 16;
    return v.f;
}
static __device__ __forceinline__ s16x8 pack8(f32x4 a, f32x4 b) {
    s16x8 r;
    r[0] = (short)f2bf(a[0]); r[1] = (short)f2bf(a[1]);
    r[2] = (short)f2bf(a[2]); r[3] = (short)f2bf(a[3]);
    r[4] = (short)f2bf(b[0]); r[5] = (short)f2bf(b[1]);
    r[6] = (short)f2bf(b[2]); r[7] = (short)f2bf(b[3]);
    return r;
}
// split x into hi (bf16) and lo (bf16 of residual)
static __device__ __forceinline__ void split8(f32x4 a, f32x4 b, s16x8* hi, s16x8* lo) {
    s16x8 h, l;
#pragma unroll
    for (int e = 0; e < 4; e++) {
        unsigned short hh = f2bf(a[e]); h[e] = (short)hh;
        l[e] = (short)f2bf(a[e] - bf2f(hh));
    }
#pragma unroll
    for (int e = 0; e < 4; e++) {
        unsigned short hh = f2bf(b[e]); h[4 + e] = (short)hh;
        l[4 + e] = (short)f2bf(b[e] - bf2f(hh));
    }
    *hi = h; *lo = l;
}
static __device__ __forceinline__ f32x4 mfma16(s16x8 a, s16x8 b, f32x4 c) {
    return __builtin_amdgcn_mfma_f32_16x16x32_bf16(a, b, c, 0, 0, 0);
}

// ---------------------------------------------------------------------------
// C[m][n] = A[m][:]·W[n][:] (+bias) (tanh?) ; K = 512 fixed.
// 128x128 tile, BK=64, 4 waves, each wave 64x64 (4x4 16x16x32 MFMA frags).
// ---------------------------------------------------------------------------
template<int SPLIT, int TANH, int BIAS, int AIN, int OUTBF16>
__global__ __launch_bounds__(256, 2)
void gemm_k(const void* __restrict__ Ap, const float* __restrict__ Wp,
            const float* __restrict__ bias, void* __restrict__ outp,
            int M, int N)
{
    const int bm = blockIdx.x, bn = blockIdx.y;
    const int tid = threadIdx.x;
    const int w = tid >> 6, lane = tid & 63;
    const int l15 = lane & 15, l4 = lane >> 4;

    __shared__ unsigned short Al[128 * 72 * (SPLIT ? 2 : 1)];
    __shared__ unsigned short Wl[128 * 72 * (SPLIT ? 2 : 1)];
    const int LOFS = 128 * 72;   // lo-plane offset (elems)

    f32x4 acc[4][4];
#pragma unroll
    for (int i = 0; i < 4; i++)
#pragma unroll
        for (int j = 0; j < 4; j++) acc[i][j] = (f32x4){0.f, 0.f, 0.f, 0.f};

    const int srow = tid >> 1, shalf = tid & 1;
    const float* Asrc = (const float*)Ap + (size_t)(bm * 128 + srow) * 512 + shalf * 32;
    const unsigned short* Asrcb = (const unsigned short*)Ap + (size_t)(bm * 128 + srow) * 512 + shalf * 32;
    const float* Wsrc = Wp + (size_t)(bn * 128 + srow) * 512 + shalf * 32;
    unsigned short* Adst = Al + srow * 72 + shalf * 32;
    unsigned short* Wdst = Wl + srow * 72 + shalf * 32;

    for (int k0 = 0; k0 < 512; k0 += 64) {
        __syncthreads();
        if (AIN) {
#pragma unroll
            for (int j = 0; j < 4; j++)
                *(s16x8*)(Adst + j * 8) = *(const s16x8*)(Asrcb + k0 + j * 8);
        } else if (SPLIT) {
#pragma unroll
            for (int j = 0; j < 4; j++) {
                f32x4 x = *(const f32x4*)(Asrc + k0 + j * 8);
                f32x4 y = *(const f32x4*)(Asrc + k0 + j * 8 + 4);
                s16x8 hi, lo; split8(x, y, &hi, &lo);
                *(s16x8*)(Adst + j * 8) = hi;
                *(s16x8*)(Adst + LOFS + j * 8) = lo;
            }
        } else {
#pragma unroll
            for (int j = 0; j < 4; j++) {
                f32x4 x = *(const f32x4*)(Asrc + k0 + j * 8);
                f32x4 y = *(const f32x4*)(Asrc + k0 + j * 8 + 4);
                *(s16x8*)(Adst + j * 8) = pack8(x, y);
            }
        }
        if (SPLIT) {
#pragma unroll
            for (int j = 0; j < 4; j++) {
                f32x4 x = *(const f32x4*)(Wsrc + k0 + j * 8);
                f32x4 y = *(const f32x4*)(Wsrc + k0 + j * 8 + 4);
                s16x8 hi, lo; split8(x, y, &hi, &lo);
                *(s16x8*)(Wdst + j * 8) = hi;
                *(s16x8*)(Wdst + LOFS + j * 8) = lo;
            }
        } else {
#pragma unroll
            for (int j = 0; j < 4; j++) {
                f32x4 x = *(const f32x4*)(Wsrc + k0 + j * 8);
                f32x4 y = *(const f32x4*)(Wsrc + k0 + j * 8 + 4);
                *(s16x8*)(Wdst + j * 8) = pack8(x, y);
            }
        }
        __syncthreads();

#pragma unroll
        for (int kt = 0; kt < 2; kt++) {
            s16x8 afh[4], bfh[4];
#pragma unroll
            for (int mb = 0; mb < 4; mb++)
                afh[mb] = *(const s16x8*)(Al + ((w & 1) * 64 + mb * 16 + l15) * 72 + kt * 32 + l4 * 8);
#pragma unroll
            for (int nb = 0; nb < 4; nb++)
                bfh[nb] = *(const s16x8*)(Wl + ((w >> 1) * 64 + nb * 16 + l15) * 72 + kt * 32 + l4 * 8);
            if (SPLIT) {
                s16x8 afl[4], bfl[4];
#pragma unroll
                for (int mb = 0; mb < 4; mb++)
                    afl[mb] = *(const s16x8*)(Al + LOFS + ((w & 1) * 64 + mb * 16 + l15) * 72 + kt * 32 + l4 * 8);
#pragma unroll
                for (int nb = 0; nb < 4; nb++)
                    bfl[nb] = *(const s16x8*)(Wl + LOFS + ((w >> 1) * 64 + nb * 16 + l15) * 72 + kt * 32 + l4 * 8);
#pragma unroll
                for (int mb = 0; mb < 4; mb++)
#pragma unroll
                    for (int nb = 0; nb < 4; nb++) {
                        acc[mb][nb] = mfma16(afh[mb], bfh[nb], acc[mb][nb]);
                        acc[mb][nb] = mfma16(afh[mb], bfl[nb], acc[mb][nb]);
                        acc[mb][nb] = mfma16(afl[mb], bfh[nb], acc[mb][nb]);
                    }
            } else {
#pragma unroll
                for (int mb = 0; mb < 4; mb++)
#pragma unroll
                    for (int nb = 0; nb < 4; nb++)
                        acc[mb][nb] = mfma16(afh[mb], bfh[nb], acc[mb][nb]);
            }
        }
    }

    const int m0 = bm * 128 + (w & 1) * 64;
    const int n0 = bn * 128 + (w >> 1) * 64;
#pragma unroll
    for (int nb = 0; nb < 4; nb++) {
        float bv = 0.0f;
        const int n = n0 + nb * 16 + l15;
        if (BIAS) bv = bias[n];
#pragma unroll
        for (int mb = 0; mb < 4; mb++) {
#pragma unroll
            for (int i = 0; i < 4; i++) {
                const int m = m0 + mb * 16 + l4 * 4 + i;
                float vv = acc[mb][nb][i];
                if (BIAS) vv += bv;
                if (TANH) vv = tanh_fast(vv);
                if (OUTBF16) ((unsigned short*)outp)[(size_t)m * N + n] = f2bf(vv);
                else        ((float*)outp)[(size_t)m * N + n] = vv;
            }
        }
    }
}

// ---------------------------------------------------------------------------
// Fused attention: block = (t-tile of 16, b). 512 threads.
// ---------------------------------------------------------------------------
__global__ __launch_bounds__(512, 4)
void att_k(const float* __restrict__ Pt, const float* __restrict__ Qt,
           const float* __restrict__ Vv, const float* __restrict__ vin,
           unsigned short* __restrict__ cbuf)
{
    const int tblk = blockIdx.x, b = blockIdx.y;
    const int tid = threadIdx.x;
    const int w = tid >> 6, lane = tid & 63;
    const int t_in = lane >> 5, sl = lane & 31;
    const int t_loc = w * 2 + t_in;          // 0..15
    const int tg = tblk * 16 + t_loc;        // global t

    __shared__ float sbuf[16][513];
    __shared__ float qst[8][640];
    __shared__ float zinv[16];

    float Pa[16], Vb[16], VbA[16];
    {
        const float* pp = Pt + ((size_t)tg * 64 + b) * 512 + sl * 16;
        const float* vb = Vv + (size_t)b * 512 + sl * 16;
#pragma unroll
        for (int j = 0; j < 4; j++) {
            f32x4 x = *(const f32x4*)(pp + j * 4);
            f32x4 y = *(const f32x4*)(vb + j * 4);
#pragma unroll
            for (int e = 0; e < 4; e++) { Pa[j * 4 + e] = x[e]; Vb[j * 4 + e] = y[e]; }
        }
#pragma unroll
        for (int e = 0; e < 16; e++) VbA[e] = Vb[e] * Pa[e];
    }

    // ---- Phase A: logits (tanh addition formula; 1+A*B > 0 always since |A|,|B|<1) ----
    for (int l0 = 0; l0 < 512; l0 += 8) {
        __syncthreads();
        {
            const int row = tid >> 6;
            const int cb = (tid & 63) * 8;
            const float* src = Qt + ((size_t)(l0 + row) * 64 + b) * 512 + cb;
            const int f0 = cb + 4 * (cb >> 4);
            *(f32x4*)(&qst[row][f0])     = *(const f32x4*)(src);
            *(f32x4*)(&qst[row][f0 + 4]) = *(const f32x4*)(src + 4);
        }
        __syncthreads();
        for (int l = 0; l < 8; l++) {
            const float* qrow = &qst[l][sl * 20];
            float a0 = 0.f, a1 = 0.f, a2 = 0.f, a3 = 0.f;
#pragma unroll
            for (int j = 0; j < 4; j++) {
                f32x4 q = *(const f32x4*)(qrow + j * 4);
                {
                    float d = fmaf(Pa[4 * j + 0], q[0], 1.0f);
                    a0 = fmaf(fmaf(Vb[4 * j + 0], q[0], VbA[4 * j + 0]), rcp_fast(d), a0);
                }
                {
                    float d = fmaf(Pa[4 * j + 1], q[1], 1.0f);
                    a1 = fmaf(fmaf(Vb[4 * j + 1], q[1], VbA[4 * j + 1]), rcp_fast(d), a1);
                }
                {
                    float d = fmaf(Pa[4 * j + 2], q[2], 1.0f);
                    a2 = fmaf(fmaf(Vb[4 * j + 2], q[2], VbA[4 * j + 2]), rcp_fast(d), a2);
                }
                {
                    float d = fmaf(Pa[4 * j + 3], q[3], 1.0f);
                    a3 = fmaf(fmaf(Vb[4 * j + 3], q[3], VbA[4 * j + 3]), rcp_fast(d), a3);
                }
            }
            float accp = (a0 + a1) + (a2 + a3);
#pragma unroll
            for (int m = 1; m < 32; m <<= 1) accp += __shfl_xor(accp, m, 64);
            if (sl == 0) sbuf[t_loc][l0 + l] = accp;
        }
    }
    __syncthreads();

    // ---- Phase B: softmax over l ----
    {
        const int tr = tid >> 5;
        const int i = tid & 31;
        float m = -1e30f;
        for (int l = i; l < 512; l += 32) m = fmaxf(m, sbuf[tr][l]);
#pragma unroll
        for (int mm = 1; mm < 32; mm <<= 1) m = fmaxf(m, __shfl_xor(m, mm, 64));
        float z = 0.0f;
        for (int l = i; l < 512; l += 32) {
            float e = __expf(sbuf[tr][l] - m);
            sbuf[tr][l] = e;
            z += e;
        }
#pragma unroll
        for (int mm = 1; mm < 32; mm <<= 1) z += __shfl_xor(z, mm, 64);
        if (i == 0) zinv[tr] = rcp_fast(z);
    }
    __syncthreads();

    // ---- Phase C: c[t][b][:] ----
    float ca[16];
#pragma unroll
    for (int j = 0; j < 16; j++) ca[j] = 0.0f;

    for (int l0 = 0; l0 < 512; l0 += 8) {
        __syncthreads();
        {
            const int row = tid >> 6;
            const int cb = (tid & 63) * 8;
            const float* src = vin + ((size_t)(l0 + row) * 64 + b) * 512 + cb;
            const int f0 = cb + 4 * (cb >> 4);
            *(f32x4*)(&qst[row][f0])     = *(const f32x4*)(src);
            *(f32x4*)(&qst[row][f0 + 4]) = *(const f32x4*)(src + 4);
        }
        __syncthreads();
        for (int l = 0; l < 8; l++) {
            const float a = sbuf[t_loc][l0 + l];
            const float* vrow = &qst[l][sl * 20];
#pragma unroll
            for (int j = 0; j < 4; j++) {
                f32x4 x = *(const f32x4*)(vrow + j * 4);
                ca[4 * j + 0] = fmaf(a, x[0], ca[4 * j + 0]);
                ca[4 * j + 1] = fmaf(a, x[1], ca[4 * j + 1]);
                ca[4 * j + 2] = fmaf(a, x[2], ca[4 * j + 2]);
                ca[4 * j + 3] = fmaf(a, x[3], ca[4 * j + 3]);
            }
        }
    }
    const float zi = zinv[t_loc];
    unsigned short* co = cbuf + ((size_t)tg * 64 + b) * 512 + sl * 16;
#pragma unroll
    for (int j = 0; j < 4; j++) {
        s16x4 o;
        o[0] = (short)f2bf(ca[4 * j + 0] * zi);
        o[1] = (short)f2bf(ca[4 * j + 1] * zi);
        o[2] = (short)f2bf(ca[4 * j + 2] * zi);
        o[3] = (short)f2bf(ca[4 * j + 3] * zi);
        *(s16x4*)(co + j * 4) = o;
    }
}

// ---------------------------------------------------------------------------
// GRU recurrence. 256 one-wave blocks: group grp = bid&7 (8 b's), sub sb = bid>>3
// owns output slice jj = sb*16. W_hh slice register-resident as MFMA A-frags.
// Per-step sync: one release fence + relaxed add (producer); relaxed polls +
// one acquire fence (consumer); bounded fast-poll with acquire-poll fallback
// (r2-proven path) for hang safety.
// ---------------------------------------------------------------------------
__global__ __launch_bounds__(64, 1)
void rec_k(const unsigned short* __restrict__ Gi,
           const float* __restrict__ Whh, const float* __restrict__ bhh,
           const float* __restrict__ h0,
           unsigned short* __restrict__ hbf,
           unsigned int* __restrict__ bar,
           float* __restrict__ hs)
{
    const int grp = blockIdx.x & 7;
    const int sb = blockIdx.x >> 3;      // 0..31
    const int lane = threadIdx.x;
    const int l15 = lane & 15, l4 = lane >> 4;
    const int jj = sb * 16;
    const int bcol = l15 & 7;
    const int b = grp * 8 + bcol;
    const int jrow = l4 * 4;

    s16x8 wf[3][16];
#pragma unroll
    for (int g = 0; g < 3; g++) {
        const float* wr = Whh + (size_t)(g * 512 + jj + l15) * 512 + l4 * 8;
#pragma unroll
        for (int kt = 0; kt < 16; kt++) {
            f32x4 x = *(const f32x4*)(wr + kt * 32);
            f32x4 y = *(const f32x4*)(wr + kt * 32 + 4);
            wf[g][kt] = pack8(x, y);
        }
    }

    float bh_r[4], bh_z[4], bh_n[4];
#pragma unroll
    for (int i = 0; i < 4; i++) {
        bh_r[i] = bhh[jj + jrow + i];
        bh_z[i] = bhh[512 + jj + jrow + i];
        bh_n[i] = bhh[1024 + jj + jrow + i];
    }
    float hp[4];
    {
        f32x4 x = *(const f32x4*)(h0 + (size_t)b * 512 + jj + jrow);
        hp[0] = x[0]; hp[1] = x[1]; hp[2] = x[2]; hp[3] = x[3];
    }
    unsigned int* mybar = bar + grp * 512;
    const bool writer = (l15 < 8);

    // Gi for t=0
    s16x4 g0, g1, g2;
    {
        const unsigned short* gp = Gi + (size_t)b * 1536 + jj + jrow;
        g0 = *(const s16x4*)(gp);
        g1 = *(const s16x4*)(gp + 512);
        g2 = *(const s16x4*)(gp + 1024);
    }

    unsigned int fastlim = 256;

    for (int t = 0; t < 512; t++) {
        s16x8 hfrag[16];
        if (t == 0) {
            const float* hr = h0 + (size_t)b * 512 + l4 * 8;
#pragma unroll
            for (int kt = 0; kt < 16; kt++) {
                f32x4 x = *(const f32x4*)(hr + kt * 32);
                f32x4 y = *(const f32x4*)(hr + kt * 32 + 4);
                hfrag[kt] = pack8(x, y);
            }
        } else {
            const unsigned short* hr = hbf + ((size_t)((t & 1) * 64 + b)) * 512 + l4 * 8;
#pragma unroll
            for (int kt = 0; kt < 16; kt++)
                hfrag[kt] = *(const s16x8*)(hr + kt * 32);
        }

        f32x4 acc0 = {0.f, 0.f, 0.f, 0.f};
        f32x4 acc1 = {0.f, 0.f, 0.f, 0.f};
        f32x4 acc2 = {0.f, 0.f, 0.f, 0.f};
#pragma unroll
        for (int kt = 0; kt < 16; kt++) {
            acc0 = mfma16(wf[0][kt], hfrag[kt], acc0);
            acc1 = mfma16(wf[1][kt], hfrag[kt], acc1);
            acc2 = mfma16(wf[2][kt], hfrag[kt], acc2);
        }

        f32x4 hv;
        if (writer) {
            unsigned short* hbo = hbf + ((size_t)(((t + 1) & 1) * 64 + b)) * 512 + jj + jrow;
            s16x4 hb;
#pragma unroll
            for (int i = 0; i < 4; i++) {
                float rr = sigmoid_fast(bf2f((unsigned short)g0[i]) + acc0[i] + bh_r[i]);
                float zz = sigmoid_fast(bf2f((unsigned short)g1[i]) + acc1[i] + bh_z[i]);
                float nn = tanh_fast(bf2f((unsigned short)g2[i]) + rr * (acc2[i] + bh_n[i]));
                float hn = fmaf(zz, hp[i] - nn, nn);
                hp[i] = hn;
                hv[i] = hn;
                hb[i] = (short)f2bf(hn);
            }
            *(s16x4*)hbo = hb;                    // cross-block visible h (bf16)
        }
        float* hso = hs + ((size_t)t * 64 + b) * 512 + jj + jrow;

        if (t < 511) {
            // publish hbf, signal arrival
            __builtin_amdgcn_fence(__ATOMIC_RELEASE, "agent");
            if (lane == 0)
                __hip_atomic_fetch_add(mybar + t, 1u, __ATOMIC_RELAXED, __HIP_MEMORY_SCOPE_AGENT);
            // hs store drains during the poll (not cross-block read)
            if (writer) *(f32x4*)hso = hv;
            // prefetch Gi[t+1] (h-independent) under the barrier wait
            s16x4 n0, n1, n2;
            {
                const unsigned short* gp = Gi + ((size_t)(t + 1) * 64 + b) * 1536 + jj + jrow;
                n0 = *(const s16x4*)(gp);
                n1 = *(const s16x4*)(gp + 512);
                n2 = *(const s16x4*)(gp + 1024);
            }
            // fast relaxed poll (no per-iteration cache maintenance)
            bool done = false;
            for (unsigned it = 0; it < fastlim; ++it) {
                if (__hip_atomic_load(mybar + t, __ATOMIC_RELAXED, __HIP_MEMORY_SCOPE_AGENT) >= 32u) {
                    done = true; break;
                }
                __builtin_amdgcn_s_sleep(1);
            }
            if (!done) {
                // fallback: r2-proven acquire-poll (handles any staleness), never gives up
                fastlim = 4;
                while (__hip_atomic_load(mybar + t, __ATOMIC_ACQUIRE, __HIP_MEMORY_SCOPE_AGENT) < 32u)
                    __builtin_amdgcn_s_sleep(2);
            }
            __builtin_amdgcn_fence(__ATOMIC_ACQUIRE, "agent");
            g0 = n0; g1 = n1; g2 = n2;
        } else {
            if (writer) *(f32x4*)hso = hv;
        }
    }
}

// ---------------------------------------------------------------------------
// ws layout (bytes):
//   Pt : [0, 64Mi)            f32  L*B x 512
//   Qt : [64Mi, 128Mi)        f32
//   c  : [128Mi, 160Mi)       bf16 L*B x 512
//   Gi : [0, 96Mi)            bf16 L*B x 1536  (overlays Pt/Qt, dead by then)
//   hbf: [160Mi, +128Ki)      bf16 2 x 64 x 512
//   bar: [160Mi+128Ki, +16Ki) u32  8 x 512
// total ~160.2 MiB
// ---------------------------------------------------------------------------
extern "C" void kernel_launch(void* const* d_in, const int* in_sizes, int n_in,
                              void* d_out, int out_size, void* d_ws, size_t ws_size,
                              hipStream_t stream)
{
    (void)in_sizes; (void)n_in; (void)out_size; (void)ws_size;
    const float* v   = (const float*)d_in[0];
    const float* h0  = (const float*)d_in[1];
    const float* Vv  = (const float*)d_in[2];
    const float* Wp  = (const float*)d_in[3];
    const float* Wp_ = (const float*)d_in[4];
    const float* Wih = (const float*)d_in[5];
    const float* Whh = (const float*)d_in[6];
    const float* bih = (const float*)d_in[7];
    const float* bhh = (const float*)d_in[8];
    float* hs = (float*)d_out;

    char* ws = (char*)d_ws;
    float* Pt = (float*)(ws);
    float* Qt = (float*)(ws + 67108864ULL);
    unsigned short* cb  = (unsigned short*)(ws + 134217728ULL);
    unsigned short* Gi  = (unsigned short*)(ws);
    unsigned short* hbf = (unsigned short*)(ws + 167772160ULL);
    unsigned int*   bar = (unsigned int*)(ws + 167772160ULL + 131072ULL);

    hipMemsetAsync(bar, 0, 4096 * sizeof(unsigned int), stream);

    dim3 gpq(256, 4, 1);
    gemm_k<1, 1, 0, 0, 0><<<gpq, 256, 0, stream>>>(v, Wp, nullptr, Pt, 32768, 512);
    gemm_k<1, 1, 0, 0, 0><<<gpq, 256, 0, stream>>>(v, Wp_, nullptr, Qt, 32768, 512);

    att_k<<<dim3(32, 64), 512, 0, stream>>>(Pt, Qt, Vv, v, cb);

    gemm_k<0, 0, 1, 1, 1><<<dim3(256, 12), 256, 0, stream>>>(cb, Wih, bih, Gi, 32768, 1536);

    rec_k<<<dim3(256), 64, 0, stream>>>(Gi, Whh, bhh, h0, hbf, bar, hs);
}